// Round 11
// baseline (147.613 us; speedup 1.0000x reference)
//
#include <hip/hip_runtime.h>
#include <hip/hip_fp16.h>

// HGNN aggregation: out = x + segment_sum(x[src_idx], dst_idx)
// x: [100000, 128] f32; src_idx/dst_idx: [2,000,000] int32.
//
// Round 11: round-10 design, compile fix (__half2 bit-cast instead of the
// nonexistent __ushort2_as_half2).
//   1. memset cursors/counters
//   2. fused prep: blocks [0,nPart) partition edges into per-bucket arenas
//      (clustered reservation writes); then ALL blocks drain a work queue
//      converting x -> f16 mirror (+ zeroed pad row for predication).
//   3. aggregate: 4 blocks/bucket, 32-bin LDS counting-sort of the quarter,
//      then 4 waves x 8 nodes in PAIRS: 16 independent uint2 loads in
//      flight per half-wave, v_pk_add_f16 accumulation (2 chains/node),
//      f32 finish + exact f32 residual.
//   4. spill_apply: f32 atomics for overflow (expected 0).

constexpr int DIM = 128;
constexpr int BSHIFT = 7;            // 128 nodes per bucket
constexpr int GNODES = 1 << BSHIFT;  // 128
constexpr int MAXB = 1024;           // max buckets (N <= 131072)
constexpr int CE = 8192;             // edges per partition chunk
constexpr int CAP_MAX = 3072;        // arena slots per bucket
constexpr int QCAP = 1536;           // per-quarter sorted capacity (mean 640)
constexpr int CONVCH = 8192;         // float4s per convert queue chunk

__global__ void hgnn_fused_prep(const float4* __restrict__ x4,
                                ushort4* __restrict__ xh4, int n4,
                                const int* __restrict__ src,
                                const int* __restrict__ dst,
                                int* __restrict__ cursor,
                                int* __restrict__ arena, int cap,
                                int* __restrict__ spillCnt,
                                int2* __restrict__ spill, int spillCap,
                                int* __restrict__ qctr, int nChunks,
                                int nedges, int nbk, int nPart) {
    __shared__ int h[MAXB];
    __shared__ int lb[MAXB];
    __shared__ int chunkS;
    const int tid = threadIdx.x;

    if ((int)blockIdx.x < nPart) {
        // ---- partition phase (one CE-chunk per block) ----
        int c0 = blockIdx.x * CE;
        int c1 = min(c0 + CE, nedges);
        for (int i = tid; i < nbk; i += blockDim.x) h[i] = 0;
        __syncthreads();
        for (int i = c0 + tid; i < c1; i += blockDim.x)
            atomicAdd(&h[dst[i] >> BSHIFT], 1);
        __syncthreads();
        for (int i = tid; i < nbk; i += blockDim.x)
            lb[i] = h[i] ? atomicAdd(&cursor[i], h[i]) : 0;
        __syncthreads();
        for (int i = c0 + tid; i < c1; i += blockDim.x) {
            int s = src[i];
            int d = dst[i];
            int bk = d >> BSHIFT;
            int pos = atomicAdd(&lb[bk], 1);
            if (pos < cap) {
                arena[(size_t)bk * cap + pos] = s | ((d & (GNODES - 1)) << 17);
            } else {
                int sp = atomicAdd(spillCnt, 1);
                if (sp < spillCap) spill[sp] = make_int2(s, d);
            }
        }
    } else if ((int)blockIdx.x == nPart) {
        // zero pad row (row index N): 32 ushort4 = 256 B
        if (tid < 32) {
            ushort4 z; z.x = 0; z.y = 0; z.z = 0; z.w = 0;
            xh4[n4 + tid] = z;
        }
    }

    // ---- work-stealing convert queue (all blocks) ----
    for (;;) {
        if (tid == 0) chunkS = atomicAdd(qctr, 1);
        __syncthreads();
        int chunk = chunkS;
        __syncthreads();
        if (chunk >= nChunks) break;
        int i0 = chunk * CONVCH;
        int i1 = min(i0 + CONVCH, n4);
        for (int i = i0 + tid; i < i1; i += blockDim.x) {
            float4 v = x4[i];
            ushort4 o;
            o.x = __half_as_ushort(__float2half_rn(v.x));
            o.y = __half_as_ushort(__float2half_rn(v.y));
            o.z = __half_as_ushort(__float2half_rn(v.z));
            o.w = __half_as_ushort(__float2half_rn(v.w));
            xh4[i] = o;
        }
    }
}

// 4 blocks per bucket; block q sorts & aggregates quarter q (32 nodes).
__global__ void hgnn_aggregate(const float4* __restrict__ x4,
                               const uint2* __restrict__ xh,
                               const int* __restrict__ arena, int cap,
                               const int* __restrict__ cursor,
                               float4* __restrict__ out4, int nnodes,
                               int* __restrict__ spillCnt,
                               int2* __restrict__ spill, int spillCap) {
    __shared__ int qsorted[QCAP];
    __shared__ int hoff[33];
    __shared__ int hcur[32];

    const int b = blockIdx.x >> 2;
    const int q = blockIdx.x & 3;
    const int tid = threadIdx.x;
    const int wv = tid >> 6;
    const int lane = tid & 63;
    const int h = lane >> 5;
    const int c = lane & 31;
    const int ZROW = nnodes;          // zeroed pad row in f16 mirror

    int cnt = cursor[b];
    if (cnt > cap) cnt = cap;
    const int* ar = arena + (size_t)b * cap;

    // pass 1: 32-bin histogram of this quarter's edges
    if (tid < 32) hcur[tid] = 0;
    __syncthreads();
    for (int i = tid; i < cnt; i += blockDim.x) {
        int dl = ar[i] >> 17;
        if ((dl >> 5) == q) atomicAdd(&hcur[dl & 31], 1);
    }
    __syncthreads();

    // inclusive scan -> hoff[1..32], hoff[0] = 0
    int myc = (tid < 32) ? hcur[tid] : 0;
    if (tid < 32) hoff[tid + 1] = myc;
    if (tid == 0) hoff[0] = 0;
    __syncthreads();
    for (int off = 1; off < 32; off <<= 1) {
        int v = (tid < 32 && tid >= off) ? hoff[tid + 1 - off] : 0;
        __syncthreads();
        if (tid < 32) hoff[tid + 1] += v;
        __syncthreads();
    }
    if (tid < 32) hcur[tid] = hoff[tid];
    __syncthreads();

    // pass 2: scatter into sorted LDS list
    for (int i = tid; i < cnt; i += blockDim.x) {
        int p = ar[i];
        int dl = p >> 17;
        if ((dl >> 5) == q) {
            int pos = atomicAdd(&hcur[dl & 31], 1);
            if (pos < QCAP) {
                qsorted[pos] = p;
            } else {                       // pathological skew only
                int sp = atomicAdd(spillCnt, 1);
                if (sp < spillCap)
                    spill[sp] = make_int2(p & 0x1FFFF, (b << BSHIFT) + dl);
            }
        }
    }
    __syncthreads();

    // gather: wave wv handles nodes in pairs; f16 pk accumulation
    const int nodeBase = (b << BSHIFT) + q * 32 + wv * 8;
    const __half2 hz = __floats2half2_rn(0.f, 0.f);
    for (int r = 0; r < 8; r += 2) {
        int n0 = nodeBase + r;
        if (n0 >= nnodes) break;
        int n1 = n0 + 1;
        bool has1 = n1 < nnodes;

        int bin0 = wv * 8 + r;
        int s0 = hoff[bin0];
        int e0 = hoff[bin0 + 1];
        int s1 = hoff[bin0 + 1];
        int e1 = hoff[bin0 + 2];
        // clamp vs QCAP overflow (spilled)
        if (s0 > QCAP) s0 = QCAP;
        if (e0 > QCAP) e0 = QCAP;
        if (s1 > QCAP) s1 = QCAP;
        if (e1 > QCAP) e1 = QCAP;
        int m0 = e0 - s0;
        int m1 = has1 ? (e1 - s1) : 0;
        int mm = max(m0, m1);

        // two accumulator chains per node (break serial dep)
        __half2 a0lo = hz, a0hi = hz, b0lo = hz, b0hi = hz;
        __half2 a1lo = hz, a1hi = hz, b1lo = hz, b1hi = hz;

        for (int j = 0; j < mm; j += 16) {
#pragma unroll
            for (int k = 0; k < 8; ++k) {
                int e = j + 2 * k + h;
                int p0 = (e < m0) ? (qsorted[s0 + e] & 0x1FFFF) : ZROW;
                int p1 = (e < m1) ? (qsorted[s1 + e] & 0x1FFFF) : ZROW;
                uint2 v0 = xh[(size_t)p0 * 32 + c];
                uint2 v1 = xh[(size_t)p1 * 32 + c];
                __half2 v0lo = *reinterpret_cast<const __half2*>(&v0.x);
                __half2 v0hi = *reinterpret_cast<const __half2*>(&v0.y);
                __half2 v1lo = *reinterpret_cast<const __half2*>(&v1.x);
                __half2 v1hi = *reinterpret_cast<const __half2*>(&v1.y);
                if (k & 1) {
                    b0lo = __hadd2(b0lo, v0lo); b0hi = __hadd2(b0hi, v0hi);
                    b1lo = __hadd2(b1lo, v1lo); b1hi = __hadd2(b1hi, v1hi);
                } else {
                    a0lo = __hadd2(a0lo, v0lo); a0hi = __hadd2(a0hi, v0hi);
                    a1lo = __hadd2(a1lo, v1lo); a1hi = __hadd2(a1hi, v1hi);
                }
            }
        }

        // node n0 finish
        {
            __half2 slo = __hadd2(a0lo, b0lo);
            __half2 shi = __hadd2(a0hi, b0hi);
            float2 flo = __half22float2(slo);
            float2 fhi = __half22float2(shi);
            float ax = flo.x + __shfl_xor(flo.x, 32);
            float ay = flo.y + __shfl_xor(flo.y, 32);
            float az = fhi.x + __shfl_xor(fhi.x, 32);
            float aw = fhi.y + __shfl_xor(fhi.y, 32);
            if (h == 0) {
                float4 xv = x4[(size_t)n0 * 32 + c];
                out4[(size_t)n0 * 32 + c] =
                    make_float4(xv.x + ax, xv.y + ay, xv.z + az, xv.w + aw);
            }
        }
        // node n1 finish
        if (has1) {
            __half2 slo = __hadd2(a1lo, b1lo);
            __half2 shi = __hadd2(a1hi, b1hi);
            float2 flo = __half22float2(slo);
            float2 fhi = __half22float2(shi);
            float ax = flo.x + __shfl_xor(flo.x, 32);
            float ay = flo.y + __shfl_xor(flo.y, 32);
            float az = fhi.x + __shfl_xor(fhi.x, 32);
            float aw = fhi.y + __shfl_xor(fhi.y, 32);
            if (h == 0) {
                float4 xv = x4[(size_t)n1 * 32 + c];
                out4[(size_t)n1 * 32 + c] =
                    make_float4(xv.x + ax, xv.y + ay, xv.z + az, xv.w + aw);
            }
        }
    }
}

// handles overflow edges (expected none on this data); exact f32 path
__global__ void hgnn_spill_apply(const float4* __restrict__ x4,
                                 const int* __restrict__ spillCnt,
                                 const int2* __restrict__ spill,
                                 float* __restrict__ out, int spillCap) {
    int n = *spillCnt;
    if (n > spillCap) n = spillCap;
    int i = blockIdx.x * blockDim.x + threadIdx.x;
    int stride = gridDim.x * blockDim.x;
    for (int k = i; k < n * 32; k += stride) {
        int e = k >> 5;
        int cc = k & 31;
        int2 sd = spill[e];
        float4 v = x4[(size_t)sd.x * 32 + cc];
        float* o = out + (size_t)sd.y * DIM + cc * 4;
        atomicAdd(o + 0, v.x);
        atomicAdd(o + 1, v.y);
        atomicAdd(o + 2, v.z);
        atomicAdd(o + 3, v.w);
    }
}

static inline size_t align256(size_t v) { return (v + 255) & ~(size_t)255; }

extern "C" void kernel_launch(void* const* d_in, const int* in_sizes, int n_in,
                              void* d_out, int out_size, void* d_ws, size_t ws_size,
                              hipStream_t stream) {
    const float* x = (const float*)d_in[0];
    const int* src = (const int*)d_in[1];
    const int* dst = (const int*)d_in[2];
    float* out = (float*)d_out;

    const int E = in_sizes[1];                   // 2,000,000
    const int N = in_sizes[0] / DIM;             // 100,000
    const int n4 = N * (DIM / 4);                // 3.2M float4 (= ushort4 mirror elems)
    const int NBK = (N + GNODES - 1) >> BSHIFT;  // 782
    const int nPart = (E + CE - 1) / CE;         // 245 partition chunks
    const int nChunks = (n4 + CONVCH - 1) / CONVCH;

    // workspace: cursor[MAXB] + spillCnt + qctr | f16 mirror (N+1 rows) | arena | spill
    char* w = (char*)d_ws;
    size_t curBytes = align256((size_t)(MAXB + 2) * sizeof(int));
    size_t xhBytes = align256((size_t)(N + 1) * DIM * 2);   // +pad row
    size_t fixedBytes = curBytes + xhBytes;
    size_t spillReserve = 256 * 1024;

    size_t avail = (ws_size > fixedBytes + spillReserve)
                       ? (ws_size - fixedBytes - spillReserve) : 0;
    int cap = (int)((avail / sizeof(int)) / (size_t)NBK);
    if (cap > CAP_MAX) cap = CAP_MAX;
    if (cap < 64) cap = 64;    // degenerate ws; spill net keeps correctness

    int* cursor = (int*)w;                        // [NBK]
    int* spillCnt = cursor + MAXB;                // [1]
    int* qctr = cursor + MAXB + 1;                // [1]
    ushort* xh = (ushort*)(w + curBytes);         // [(N+1)*128] f16
    int* arena = (int*)(w + fixedBytes);          // [NBK*cap]
    size_t arenaBytes = align256((size_t)NBK * cap * sizeof(int));
    int2* spill = (int2*)(w + fixedBytes + arenaBytes);
    int spillCap = (int)((ws_size > fixedBytes + arenaBytes)
                             ? (ws_size - fixedBytes - arenaBytes) / sizeof(int2)
                             : 0);

    // 1) zero cursors + counters
    (void)hipMemsetAsync(cursor, 0, (size_t)(MAXB + 2) * sizeof(int), stream);

    // 2) fused: partition chunks + work-stealing f16 convert
    {
        int grid = nPart + 1024;
        hipLaunchKernelGGL(hgnn_fused_prep, dim3(grid), dim3(256), 0, stream,
                           (const float4*)x, (ushort4*)xh, n4,
                           src, dst, cursor, arena, cap,
                           spillCnt, spill, spillCap,
                           qctr, nChunks, E, NBK, nPart);
    }

    // 3) quarter-sort + paired gather-aggregate (4 blocks per bucket)
    hipLaunchKernelGGL(hgnn_aggregate, dim3(NBK * 4), dim3(256), 0, stream,
                       (const float4*)x, (const uint2*)xh, arena, cap,
                       cursor, (float4*)out, N, spillCnt, spill, spillCap);

    // 4) apply spilled edges (normally zero work)
    hipLaunchKernelGGL(hgnn_spill_apply, dim3(64), dim3(256), 0, stream,
                       (const float4*)x, spillCnt, spill, out, spillCap);
}

// Round 12
// 140.647 us; speedup vs baseline: 1.0495x; 1.0495x over previous
//
#include <hip/hip_runtime.h>
#include <hip/hip_fp16.h>

// HGNN aggregation: out = x + segment_sum(x[src_idx], dst_idx)
// x: [100000, 128] f32; src_idx/dst_idx: [2,000,000] int32.
//
// Round 12: uint4 (16B/lane) gather, 4 edges per wave-instruction.
//   1. memset cursors/counters
//   2. static fused prep: blocks [0,nPart) partition edges into per-bucket
//      arenas (clustered reservation writes); blocks [nPart,..) convert
//      x -> f16 mirror (+ zeroed pad row). Static split (round-9 style;
//      work-stealing queue regressed).
//   3. aggregate: 4 blocks/bucket, 32-bin LDS counting-sort of the quarter,
//      then 4 waves x 8 nodes in pairs; 16 lanes own a row (uint4 = 16B),
//      4 edges per load instruction, 8 loads in flight, v_pk_add_f16
//      accumulation (2 chains/node), cross-quarter shfl reduce,
//      f32 finish + exact f32 residual.
//   4. spill_apply: f32 atomics for overflow (expected 0).

constexpr int DIM = 128;
constexpr int BSHIFT = 7;            // 128 nodes per bucket
constexpr int GNODES = 1 << BSHIFT;  // 128
constexpr int MAXB = 1024;           // max buckets (N <= 131072)
constexpr int CE = 8192;             // edges per partition chunk
constexpr int CAP_MAX = 3072;        // arena slots per bucket
constexpr int QCAP = 1536;           // per-quarter sorted capacity (mean 640)

__global__ void hgnn_fused_prep(const float4* __restrict__ x4,
                                ushort4* __restrict__ xh4, int n4,
                                const int* __restrict__ src,
                                const int* __restrict__ dst,
                                int* __restrict__ cursor,
                                int* __restrict__ arena, int cap,
                                int* __restrict__ spillCnt,
                                int2* __restrict__ spill, int spillCap,
                                int nedges, int nbk, int nPart) {
    __shared__ int h[MAXB];
    __shared__ int lb[MAXB];
    const int tid = threadIdx.x;

    if ((int)blockIdx.x < nPart) {
        // ---- partition path ----
        int c0 = blockIdx.x * CE;
        int c1 = min(c0 + CE, nedges);
        for (int i = tid; i < nbk; i += blockDim.x) h[i] = 0;
        __syncthreads();
        for (int i = c0 + tid; i < c1; i += blockDim.x)
            atomicAdd(&h[dst[i] >> BSHIFT], 1);
        __syncthreads();
        for (int i = tid; i < nbk; i += blockDim.x)
            lb[i] = h[i] ? atomicAdd(&cursor[i], h[i]) : 0;
        __syncthreads();
        for (int i = c0 + tid; i < c1; i += blockDim.x) {
            int s = src[i];
            int d = dst[i];
            int bk = d >> BSHIFT;
            int pos = atomicAdd(&lb[bk], 1);
            if (pos < cap) {
                arena[(size_t)bk * cap + pos] = s | ((d & (GNODES - 1)) << 17);
            } else {
                int sp = atomicAdd(spillCnt, 1);
                if (sp < spillCap) spill[sp] = make_int2(s, d);
            }
        }
    } else {
        // ---- convert path (concurrent with partition) ----
        int bid = blockIdx.x - nPart;
        int nconv = gridDim.x - nPart;
        int i = bid * blockDim.x + tid;
        int stride = nconv * blockDim.x;
        for (int k = i; k < n4; k += stride) {
            float4 v = x4[k];
            ushort4 o;
            o.x = __half_as_ushort(__float2half_rn(v.x));
            o.y = __half_as_ushort(__float2half_rn(v.y));
            o.z = __half_as_ushort(__float2half_rn(v.z));
            o.w = __half_as_ushort(__float2half_rn(v.w));
            xh4[k] = o;
        }
        // zero pad row (row index N) for predicated gather
        if (bid == 0 && tid < 32) {
            ushort4 z; z.x = 0; z.y = 0; z.z = 0; z.w = 0;
            xh4[n4 + tid] = z;
        }
    }
}

// 4 blocks per bucket; block q sorts & aggregates quarter q (32 nodes).
__global__ void hgnn_aggregate(const float4* __restrict__ x4,
                               const uint4* __restrict__ xh16,
                               const int* __restrict__ arena, int cap,
                               const int* __restrict__ cursor,
                               float4* __restrict__ out4, int nnodes,
                               int* __restrict__ spillCnt,
                               int2* __restrict__ spill, int spillCap) {
    __shared__ int qsorted[QCAP];
    __shared__ int hoff[33];
    __shared__ int hcur[32];

    const int b = blockIdx.x >> 2;
    const int q = blockIdx.x & 3;
    const int tid = threadIdx.x;
    const int wv = tid >> 6;
    const int lane = tid & 63;
    const int qg = lane >> 4;     // quarter group 0..3 (edge selector)
    const int cl = lane & 15;     // 16 lanes x 16B = one 256B f16 row
    const int ZROW = nnodes;      // zeroed pad row in f16 mirror

    int cnt = cursor[b];
    if (cnt > cap) cnt = cap;
    const int* ar = arena + (size_t)b * cap;

    // pass 1: 32-bin histogram of this quarter's edges
    if (tid < 32) hcur[tid] = 0;
    __syncthreads();
    for (int i = tid; i < cnt; i += blockDim.x) {
        int dl = ar[i] >> 17;
        if ((dl >> 5) == q) atomicAdd(&hcur[dl & 31], 1);
    }
    __syncthreads();

    // inclusive scan -> hoff[1..32], hoff[0] = 0
    int myc = (tid < 32) ? hcur[tid] : 0;
    if (tid < 32) hoff[tid + 1] = myc;
    if (tid == 0) hoff[0] = 0;
    __syncthreads();
    for (int off = 1; off < 32; off <<= 1) {
        int v = (tid < 32 && tid >= off) ? hoff[tid + 1 - off] : 0;
        __syncthreads();
        if (tid < 32) hoff[tid + 1] += v;
        __syncthreads();
    }
    if (tid < 32) hcur[tid] = hoff[tid];
    __syncthreads();

    // pass 2: scatter into sorted LDS list
    for (int i = tid; i < cnt; i += blockDim.x) {
        int p = ar[i];
        int dl = p >> 17;
        if ((dl >> 5) == q) {
            int pos = atomicAdd(&hcur[dl & 31], 1);
            if (pos < QCAP) {
                qsorted[pos] = p;
            } else {                       // pathological skew only
                int sp = atomicAdd(spillCnt, 1);
                if (sp < spillCap)
                    spill[sp] = make_int2(p & 0x1FFFF, (b << BSHIFT) + dl);
            }
        }
    }
    __syncthreads();

    // gather: wave wv handles 8 nodes in pairs; 4 edges per load instr
    const int nodeBase = (b << BSHIFT) + q * 32 + wv * 8;
    const __half2 hz = __floats2half2_rn(0.f, 0.f);
    for (int r = 0; r < 8; r += 2) {
        int n0 = nodeBase + r;
        if (n0 >= nnodes) break;
        int n1 = n0 + 1;
        bool has1 = n1 < nnodes;

        int bin0 = wv * 8 + r;
        int s0 = hoff[bin0];
        int e0 = hoff[bin0 + 1];
        int s1 = hoff[bin0 + 1];
        int e1 = hoff[bin0 + 2];
        if (s0 > QCAP) s0 = QCAP;
        if (e0 > QCAP) e0 = QCAP;
        if (s1 > QCAP) s1 = QCAP;
        if (e1 > QCAP) e1 = QCAP;
        int m0 = e0 - s0;
        int m1 = has1 ? (e1 - s1) : 0;
        int mm = max(m0, m1);

        // two f16 accumulator chains per node
        __half2 a0[4] = {hz, hz, hz, hz}, b0[4] = {hz, hz, hz, hz};
        __half2 a1[4] = {hz, hz, hz, hz}, b1[4] = {hz, hz, hz, hz};

        for (int j = 0; j < mm; j += 16) {
#pragma unroll
            for (int kk = 0; kk < 4; ++kk) {          // n0: 16 edges
                int e = j + 4 * kk + qg;
                int p = (e < m0) ? (qsorted[s0 + e] & 0x1FFFF) : ZROW;
                uint4 v = xh16[(size_t)p * 16 + cl];
                __half2 h0 = *reinterpret_cast<const __half2*>(&v.x);
                __half2 h1 = *reinterpret_cast<const __half2*>(&v.y);
                __half2 h2 = *reinterpret_cast<const __half2*>(&v.z);
                __half2 h3 = *reinterpret_cast<const __half2*>(&v.w);
                if (kk & 1) {
                    b0[0] = __hadd2(b0[0], h0); b0[1] = __hadd2(b0[1], h1);
                    b0[2] = __hadd2(b0[2], h2); b0[3] = __hadd2(b0[3], h3);
                } else {
                    a0[0] = __hadd2(a0[0], h0); a0[1] = __hadd2(a0[1], h1);
                    a0[2] = __hadd2(a0[2], h2); a0[3] = __hadd2(a0[3], h3);
                }
            }
#pragma unroll
            for (int kk = 0; kk < 4; ++kk) {          // n1: 16 edges
                int e = j + 4 * kk + qg;
                int p = (e < m1) ? (qsorted[s1 + e] & 0x1FFFF) : ZROW;
                uint4 v = xh16[(size_t)p * 16 + cl];
                __half2 h0 = *reinterpret_cast<const __half2*>(&v.x);
                __half2 h1 = *reinterpret_cast<const __half2*>(&v.y);
                __half2 h2 = *reinterpret_cast<const __half2*>(&v.z);
                __half2 h3 = *reinterpret_cast<const __half2*>(&v.w);
                if (kk & 1) {
                    b1[0] = __hadd2(b1[0], h0); b1[1] = __hadd2(b1[1], h1);
                    b1[2] = __hadd2(b1[2], h2); b1[3] = __hadd2(b1[3], h3);
                } else {
                    a1[0] = __hadd2(a1[0], h0); a1[1] = __hadd2(a1[1], h1);
                    a1[2] = __hadd2(a1[2], h2); a1[3] = __hadd2(a1[3], h3);
                }
            }
        }

        // finish node n0: cross-quarter reduce (lanes ^16, ^32), f32 + residual
        {
            float f[8];
#pragma unroll
            for (int t = 0; t < 4; ++t) {
                __half2 s = __hadd2(a0[t], b0[t]);
                int si = *reinterpret_cast<int*>(&s);
                int sx = __shfl_xor(si, 16);
                s = __hadd2(s, *reinterpret_cast<__half2*>(&sx));
                si = *reinterpret_cast<int*>(&s);
                sx = __shfl_xor(si, 32);
                s = __hadd2(s, *reinterpret_cast<__half2*>(&sx));
                float2 fv = __half22float2(s);
                f[2 * t] = fv.x;
                f[2 * t + 1] = fv.y;
            }
            if (qg == 0) {
                float4 xa = x4[(size_t)n0 * 32 + 2 * cl];
                float4 xb = x4[(size_t)n0 * 32 + 2 * cl + 1];
                out4[(size_t)n0 * 32 + 2 * cl] =
                    make_float4(xa.x + f[0], xa.y + f[1], xa.z + f[2], xa.w + f[3]);
                out4[(size_t)n0 * 32 + 2 * cl + 1] =
                    make_float4(xb.x + f[4], xb.y + f[5], xb.z + f[6], xb.w + f[7]);
            }
        }
        // finish node n1
        if (has1) {
            float f[8];
#pragma unroll
            for (int t = 0; t < 4; ++t) {
                __half2 s = __hadd2(a1[t], b1[t]);
                int si = *reinterpret_cast<int*>(&s);
                int sx = __shfl_xor(si, 16);
                s = __hadd2(s, *reinterpret_cast<__half2*>(&sx));
                si = *reinterpret_cast<int*>(&s);
                sx = __shfl_xor(si, 32);
                s = __hadd2(s, *reinterpret_cast<__half2*>(&sx));
                float2 fv = __half22float2(s);
                f[2 * t] = fv.x;
                f[2 * t + 1] = fv.y;
            }
            if (qg == 0) {
                float4 xa = x4[(size_t)n1 * 32 + 2 * cl];
                float4 xb = x4[(size_t)n1 * 32 + 2 * cl + 1];
                out4[(size_t)n1 * 32 + 2 * cl] =
                    make_float4(xa.x + f[0], xa.y + f[1], xa.z + f[2], xa.w + f[3]);
                out4[(size_t)n1 * 32 + 2 * cl + 1] =
                    make_float4(xb.x + f[4], xb.y + f[5], xb.z + f[6], xb.w + f[7]);
            }
        }
    }
}

// handles overflow edges (expected none on this data); exact f32 path
__global__ void hgnn_spill_apply(const float4* __restrict__ x4,
                                 const int* __restrict__ spillCnt,
                                 const int2* __restrict__ spill,
                                 float* __restrict__ out, int spillCap) {
    int n = *spillCnt;
    if (n > spillCap) n = spillCap;
    int i = blockIdx.x * blockDim.x + threadIdx.x;
    int stride = gridDim.x * blockDim.x;
    for (int k = i; k < n * 32; k += stride) {
        int e = k >> 5;
        int cc = k & 31;
        int2 sd = spill[e];
        float4 v = x4[(size_t)sd.x * 32 + cc];
        float* o = out + (size_t)sd.y * DIM + cc * 4;
        atomicAdd(o + 0, v.x);
        atomicAdd(o + 1, v.y);
        atomicAdd(o + 2, v.z);
        atomicAdd(o + 3, v.w);
    }
}

static inline size_t align256(size_t v) { return (v + 255) & ~(size_t)255; }

extern "C" void kernel_launch(void* const* d_in, const int* in_sizes, int n_in,
                              void* d_out, int out_size, void* d_ws, size_t ws_size,
                              hipStream_t stream) {
    const float* x = (const float*)d_in[0];
    const int* src = (const int*)d_in[1];
    const int* dst = (const int*)d_in[2];
    float* out = (float*)d_out;

    const int E = in_sizes[1];                   // 2,000,000
    const int N = in_sizes[0] / DIM;             // 100,000
    const int n4 = N * (DIM / 4);                // 3.2M float4 (= ushort4 mirror elems)
    const int NBK = (N + GNODES - 1) >> BSHIFT;  // 782
    const int nPart = (E + CE - 1) / CE;         // 245 partition chunks

    // workspace: cursor[MAXB] + spillCnt | f16 mirror (N+1 rows) | arena | spill
    char* w = (char*)d_ws;
    size_t curBytes = align256((size_t)(MAXB + 1) * sizeof(int));
    size_t xhBytes = align256((size_t)(N + 1) * DIM * 2);   // +pad row
    size_t fixedBytes = curBytes + xhBytes;
    size_t spillReserve = 256 * 1024;

    size_t avail = (ws_size > fixedBytes + spillReserve)
                       ? (ws_size - fixedBytes - spillReserve) : 0;
    int cap = (int)((avail / sizeof(int)) / (size_t)NBK);
    if (cap > CAP_MAX) cap = CAP_MAX;
    if (cap < 64) cap = 64;    // degenerate ws; spill net keeps correctness

    int* cursor = (int*)w;                        // [NBK]
    int* spillCnt = cursor + MAXB;                // [1]
    ushort* xh = (ushort*)(w + curBytes);         // [(N+1)*128] f16
    int* arena = (int*)(w + fixedBytes);          // [NBK*cap]
    size_t arenaBytes = align256((size_t)NBK * cap * sizeof(int));
    int2* spill = (int2*)(w + fixedBytes + arenaBytes);
    int spillCap = (int)((ws_size > fixedBytes + arenaBytes)
                             ? (ws_size - fixedBytes - arenaBytes) / sizeof(int2)
                             : 0);

    // 1) zero cursors + counters
    (void)hipMemsetAsync(cursor, 0, (size_t)(MAXB + 1) * sizeof(int), stream);

    // 2) static fused: partition (blocks 0..nPart) || f16 convert (rest)
    {
        int grid = nPart + 1792;
        hipLaunchKernelGGL(hgnn_fused_prep, dim3(grid), dim3(256), 0, stream,
                           (const float4*)x, (ushort4*)xh, n4,
                           src, dst, cursor, arena, cap,
                           spillCnt, spill, spillCap, E, NBK, nPart);
    }

    // 3) quarter-sort + 16B-lane gather-aggregate (4 blocks per bucket)
    hipLaunchKernelGGL(hgnn_aggregate, dim3(NBK * 4), dim3(256), 0, stream,
                       (const float4*)x, (const uint4*)xh, arena, cap,
                       cursor, (float4*)out, N, spillCnt, spill, spillCap);

    // 4) apply spilled edges (normally zero work)
    hipLaunchKernelGGL(hgnn_spill_apply, dim3(64), dim3(256), 0, stream,
                       (const float4*)x, spillCnt, spill, out, spillCap);
}